// Round 1
// baseline (35.524 us; speedup 1.0000x reference)
//
#include <hip/hip_runtime.h>

#define B_ 32
#define PHONE_LEN_ 600
#define T_ 4096
#define H_ 256

// Kernel 1: per-batch-row inclusive scan of change-flags -> idx[b][t].
// One wave (64 lanes) per row; each lane owns 64 consecutive elements.
__global__ __launch_bounds__(64) void idx_kernel(const int* __restrict__ align,
                                                 int* __restrict__ idx) {
    const int b = blockIdx.x;
    const int lane = threadIdx.x;            // 0..63
    const int* a = align + (size_t)b * T_;
    const int base = lane * 64;

    int vals[64];
    int prev = (base == 0) ? 0 : a[base - 1];
    int sum = 0;
#pragma unroll
    for (int i = 0; i < 64; i += 4) {
        int4 v = *reinterpret_cast<const int4*>(a + base + i);
        sum += (v.x != prev); vals[i + 0] = sum; prev = v.x;
        sum += (v.y != prev); vals[i + 1] = sum; prev = v.y;
        sum += (v.z != prev); vals[i + 2] = sum; prev = v.z;
        sum += (v.w != prev); vals[i + 3] = sum; prev = v.w;
    }

    // inclusive wave scan of per-lane totals
    int scan = sum;
#pragma unroll
    for (int off = 1; off < 64; off <<= 1) {
        int n = __shfl_up(scan, off, 64);
        if (lane >= off) scan += n;
    }
    const int excl = scan - sum;             // exclusive prefix for this lane

    int* o = idx + (size_t)b * T_ + base;
#pragma unroll
    for (int i = 0; i < 64; i += 4) {
        int4 r;
        r.x = vals[i + 0] + excl;
        r.y = vals[i + 1] + excl;
        r.z = vals[i + 2] + excl;
        r.w = vals[i + 3] + excl;
        *reinterpret_cast<int4*>(o + i) = r;
    }
}

// Kernel 2: fused gather + three tiny Linear(1->H) projections.
// Block = 256 threads (4 waves). lane covers H via float4 (64*4 = 256).
// Each block handles 16 consecutive t for one batch b (4 t per wave).
__global__ __launch_bounds__(256) void fuse_kernel(
    const float* __restrict__ enc,    // [B, PHONE_LEN, H]
    const float* __restrict__ pitch,  // [B, T]
    const float* __restrict__ beats,  // [B, T]
    const float* __restrict__ wp, const float* __restrict__ bp,
    const float* __restrict__ wb, const float* __restrict__ bb,
    const float* __restrict__ ws, const float* __restrict__ bs,
    const int* __restrict__ idx,      // [B, T]
    float* __restrict__ out) {        // [B, T, H]
    const int lane = threadIdx.x & 63;
    const int warp = threadIdx.x >> 6;       // 0..3
    const int b = blockIdx.y;
    const int t0 = blockIdx.x * 16;
    const int h4 = lane * 4;

    const float4 w_p = *reinterpret_cast<const float4*>(wp + h4);
    const float4 w_b = *reinterpret_cast<const float4*>(wb + h4);
    const float4 w_s = *reinterpret_cast<const float4*>(ws + h4);
    float4 bsum;
    {
        const float4 b1 = *reinterpret_cast<const float4*>(bp + h4);
        const float4 b2 = *reinterpret_cast<const float4*>(bb + h4);
        const float4 b3 = *reinterpret_cast<const float4*>(bs + h4);
        bsum.x = b1.x + b2.x + b3.x;
        bsum.y = b1.y + b2.y + b3.y;
        bsum.z = b1.z + b2.z + b3.z;
        bsum.w = b1.w + b2.w + b3.w;
    }

    const float invT = 1.0f / (float)T_;
#pragma unroll
    for (int tt = warp; tt < 16; tt += 4) {
        const int t = t0 + tt;
        const size_t bt = (size_t)b * T_ + t;
        const int iv = idx[bt];               // wave-uniform scalar
        const float pv = pitch[bt];
        const float bv = beats[bt];
        const float psc = (float)t * invT;

        const float4 e = *reinterpret_cast<const float4*>(
            enc + ((size_t)b * PHONE_LEN_ + iv) * H_ + h4);

        float4 r;
        r.x = e.x + pv * w_p.x + bv * w_b.x + psc * w_s.x + bsum.x;
        r.y = e.y + pv * w_p.y + bv * w_b.y + psc * w_s.y + bsum.y;
        r.z = e.z + pv * w_p.z + bv * w_b.z + psc * w_s.z + bsum.z;
        r.w = e.w + pv * w_p.w + bv * w_b.w + psc * w_s.w + bsum.w;

        *reinterpret_cast<float4*>(out + bt * H_ + h4) = r;
    }
}

extern "C" void kernel_launch(void* const* d_in, const int* in_sizes, int n_in,
                              void* d_out, int out_size, void* d_ws, size_t ws_size,
                              hipStream_t stream) {
    const float* enc   = (const float*)d_in[0];
    const float* pitch = (const float*)d_in[1];
    const float* beats = (const float*)d_in[2];
    const float* wp    = (const float*)d_in[3];
    const float* bp    = (const float*)d_in[4];
    const float* wb    = (const float*)d_in[5];
    const float* bb    = (const float*)d_in[6];
    const float* wsp   = (const float*)d_in[7];
    const float* bsp   = (const float*)d_in[8];
    const int*   align = (const int*)d_in[9];

    int* idx = (int*)d_ws;   // B*T*4 = 512 KB scratch

    idx_kernel<<<B_, 64, 0, stream>>>(align, idx);
    fuse_kernel<<<dim3(T_ / 16, B_), 256, 0, stream>>>(
        enc, pitch, beats, wp, bp, wb, bb, wsp, bsp, idx, (float*)d_out);
}